// Round 1
// baseline (893.576 us; speedup 1.0000x reference)
//
#include <hip/hip_runtime.h>
#include <cstdint>
#include <cstddef>

#define N_NODES 256
#define N_EDGES 65536
#define NNZ_CNT 524288
#define EE_CNT  524288
#define N_MOTIF 65536
#define CH      256
#define CH_OUT  64
#define SLOPE   0.01f

static __device__ __forceinline__ float lrelu(float v){ return v >= 0.f ? v : SLOPE*v; }

// ---------------- histograms ----------------
__global__ void k_hist_inc(const int* __restrict__ src, const int* __restrict__ he,
                           int* __restrict__ d_cnt, int* __restrict__ b_cnt){
  __shared__ int ld[N_NODES];
  for (int i=threadIdx.x;i<N_NODES;i+=blockDim.x) ld[i]=0;
  __syncthreads();
  for (int i = blockIdx.x*blockDim.x+threadIdx.x; i < NNZ_CNT; i += gridDim.x*blockDim.x){
    atomicAdd(&ld[src[i]], 1);
    atomicAdd(&b_cnt[he[i]], 1);
  }
  __syncthreads();
  for (int i=threadIdx.x;i<N_NODES;i+=blockDim.x) if (ld[i]) atomicAdd(&d_cnt[i], ld[i]);
}

__global__ void k_hist_col(const int* __restrict__ ecol, int* __restrict__ degc){
  for (int i = blockIdx.x*blockDim.x+threadIdx.x; i < EE_CNT; i += gridDim.x*blockDim.x)
    atomicAdd(&degc[ecol[i]], 1);
}

// ---------------- exclusive scan over 65536 ints (3 phases) ----------------
__global__ void k_scan1(const int* __restrict__ in, int* __restrict__ tmp, int* __restrict__ bsum){
  __shared__ int l[1024];
  const int t = threadIdx.x;
  const int base = blockIdx.x*1024;
  l[t] = in[base+t];
  __syncthreads();
  for (int off=1; off<1024; off<<=1){
    int add = (t>=off) ? l[t-off] : 0;
    __syncthreads();
    l[t] += add;
    __syncthreads();
  }
  tmp[base+t] = l[t];                 // inclusive within chunk
  if (t==1023) bsum[blockIdx.x] = l[t];
}

__global__ void k_scan2(int* __restrict__ bsum){
  if (threadIdx.x==0){
    int run=0;
    for (int i=0;i<64;i++){ int v=bsum[i]; bsum[i]=run; run+=v; }
  }
}

__global__ void k_scan3(const int* __restrict__ tmp, const int* __restrict__ bsum,
                        const int* __restrict__ orig, int* __restrict__ rowptr,
                        int* __restrict__ cursor){
  int i = blockIdx.x*blockDim.x + threadIdx.x;
  if (i >= N_EDGES) return;
  int inc = tmp[i] + bsum[i>>10];     // global inclusive
  rowptr[i+1] = inc;
  cursor[i]   = inc - orig[i];        // exclusive = start of segment
  if (i==0) rowptr[0] = 0;
}

// ---------------- CSR fills ----------------
__global__ void k_fillH(const int* __restrict__ src, const int* __restrict__ he,
                        int* __restrict__ cur, int* __restrict__ colH){
  for (int i = blockIdx.x*blockDim.x+threadIdx.x; i < NNZ_CNT; i += gridDim.x*blockDim.x){
    int p = atomicAdd(&cur[he[i]], 1);
    colH[p] = src[i];
  }
}

__global__ void k_fillC(const int* __restrict__ erow, const int* __restrict__ ecol,
                        int* __restrict__ cur, int* __restrict__ rowC){
  for (int i = blockIdx.x*blockDim.x+threadIdx.x; i < EE_CNT; i += gridDim.x*blockDim.x){
    int p = atomicAdd(&cur[ecol[i]], 1);
    rowC[p] = erow[i];
  }
}

// ---------------- S = H^T diag(b_inv) H  (256x256), one wave per hyperedge ----------------
__global__ void k_S(const int* __restrict__ rowptrH, const int* __restrict__ colH,
                    float* __restrict__ S){
  int wid  = (blockIdx.x*blockDim.x + threadIdx.x) >> 6;
  int lane = threadIdx.x & 63;
  if (wid >= N_EDGES) return;
  int s0 = rowptrH[wid], s1 = rowptrH[wid+1];
  int len = s1 - s0;
  if (len <= 0) return;
  float binv = 1.0f / (float)len;
  for (int i=0;i<len;i++){
    int a = colH[s0+i]*N_NODES;
    for (int j=lane;j<len;j+=64)
      atomicAdd(&S[a + colH[s0+j]], binv);
  }
}

// ---------------- small 256x256 @ 256x256 GEMMs ----------------
// MODE 0: C = A@B ; MODE 1: C = lrelu(dinv[r]*(A@B) + bias) ; MODE 2: C = lrelu(A@B + bias)
template<int MODE>
__global__ void k_mm256(const float* __restrict__ A, const float* __restrict__ B,
                        float* __restrict__ C, const int* __restrict__ dcnt,
                        const float* __restrict__ bias){
  __shared__ float a[256];
  const int r = blockIdx.x, t = threadIdx.x;
  a[t] = A[r*256 + t];
  __syncthreads();
  float acc = 0.f;
  #pragma unroll 8
  for (int k=0;k<256;k++) acc += a[k]*B[k*256+t];
  if (MODE==1){
    int dv = dcnt[r];
    float di = dv > 0 ? 1.0f/(float)dv : 0.0f;
    acc = lrelu(acc*di + bias[t]);
  } else if (MODE==2){
    acc = lrelu(acc + bias[t]);
  }
  C[r*256+t] = acc;
}

// C = A^T @ A (256x256)
__global__ void k_atA(const float* __restrict__ A, float* __restrict__ C){
  __shared__ float a[256];
  const int r = blockIdx.x, t = threadIdx.x;
  a[t] = A[t*256 + r];
  __syncthreads();
  float acc = 0.f;
  #pragma unroll 8
  for (int k=0;k<256;k++) acc += a[k]*A[k*256+t];
  C[r*256+t] = acc;
}

// W_combo = W_lin3 @ W_out  [256,64];  b_combo = b_lin3 @ W_out + b_out
__global__ void k_combo(const float* __restrict__ W3, const float* __restrict__ b3,
                        const float* __restrict__ Wo, const float* __restrict__ bo,
                        float* __restrict__ Wc, float* __restrict__ bc){
  const int r = blockIdx.x, t = threadIdx.x; // 257 blocks x 64 threads
  if (r < 256){
    float acc = 0.f;
    #pragma unroll 8
    for (int k=0;k<128;k++) acc += W3[r*128+k]*Wo[k*64+t];
    Wc[r*64+t] = acc;
  } else {
    float acc = bo[t];
    #pragma unroll 8
    for (int k=0;k<128;k++) acc += b3[k]*Wo[k*64+t];
    bc[t] = acc;
  }
}

// ---------------- P row builder: P[c,:] = dis[c] * sum_{r in Nin(c)+self} (dis[r]/cnt[r]) H[r,:] ----------------
__global__ void k_P(const int* __restrict__ rowptrH, const int* __restrict__ colH,
                    const int* __restrict__ rowptrC, const int* __restrict__ rowC,
                    const int* __restrict__ b_cnt, const int* __restrict__ degc,
                    float* __restrict__ P){
  __shared__ float p[N_NODES];
  const int c = blockIdx.x;
  const int t = threadIdx.x;   // 64 threads
  for (int i=t;i<N_NODES;i+=64) p[i]=0.f;
  __syncthreads();
  const int e0 = rowptrC[c], e1 = rowptrC[c+1];
  for (int idx=e0-1; idx<e1; idx++){
    int r = (idx < e0) ? c : rowC[idx];      // idx==e0-1 -> self loop
    int bcr = b_cnt[r];
    float w = rsqrtf((float)(degc[r]+1)) / (float)(bcr > 0 ? bcr : 1);
    int h0 = rowptrH[r], h1 = rowptrH[r+1];
    for (int j=h0+t; j<h1; j+=64)
      atomicAdd(&p[colH[j]], w);
  }
  __syncthreads();
  float dc = rsqrtf((float)(degc[c]+1));
  for (int i=t;i<N_NODES;i+=64)
    P[(size_t)c*N_NODES + i] = p[i]*dc;
}

// ---------------- big GEMM: C[65536,Nn] = A[65536,K] @ B[K,Nn] (+bias, opt leaky) ----------------
// BM=BN=64, BK=16, 256 threads, 4x4 microtile
template<int LEAKY>
__global__ __launch_bounds__(256) void k_gemm(const float* __restrict__ A,
    const float* __restrict__ B, float* __restrict__ C,
    int K, int Nn, const float* __restrict__ bias){
  __shared__ float As[16][68];
  __shared__ float Bs[16][68];
  const int t  = threadIdx.x;
  const int m0 = blockIdx.x * 64;
  const int n0 = blockIdx.y * 64;
  const int tx = t & 15, ty = t >> 4;
  const int ar = t >> 4, ak = t & 15;   // A load: 16 rows x 16 k per pass
  const int br = t >> 6, bn = t & 63;   // B load: 4 k x 64 n per pass
  float acc[4][4] = {};
  for (int kb = 0; kb < K; kb += 16){
    #pragma unroll
    for (int i=0;i<4;i++)
      As[ak][ar + i*16] = A[(size_t)(m0 + ar + i*16)*K + kb + ak];
    #pragma unroll
    for (int i=0;i<4;i++)
      Bs[br + i*4][bn] = B[(size_t)(kb + br + i*4)*Nn + n0 + bn];
    __syncthreads();
    #pragma unroll
    for (int k=0;k<16;k++){
      const float4 a4 = *(const float4*)&As[k][ty*4];
      const float4 b4 = *(const float4*)&Bs[k][tx*4];
      const float aa[4] = {a4.x,a4.y,a4.z,a4.w};
      const float bb[4] = {b4.x,b4.y,b4.z,b4.w};
      #pragma unroll
      for (int i=0;i<4;i++)
        #pragma unroll
        for (int j=0;j<4;j++)
          acc[i][j] += aa[i]*bb[j];
    }
    __syncthreads();
  }
  #pragma unroll
  for (int i=0;i<4;i++){
    const int m = m0 + ty*4 + i;
    float4 v;
    float* vp = (float*)&v;
    #pragma unroll
    for (int j=0;j<4;j++){
      float x = acc[i][j] + bias[n0 + tx*4 + j];
      if (LEAKY) x = lrelu(x);
      vp[j] = x;
    }
    *(float4*)&C[(size_t)m*Nn + n0 + tx*4] = v;
  }
}

// ---------------- motif min-aggregate: one wave per motif ----------------
__global__ void k_mn(const float* __restrict__ y3, const int* __restrict__ msrc,
                     float* __restrict__ mn){
  int gid = blockIdx.x*blockDim.x + threadIdx.x;
  int mo = gid >> 6, q = gid & 63;
  if (mo >= N_MOTIF) return;
  int e0 = msrc[3*mo+0], e1 = msrc[3*mo+1], e2 = msrc[3*mo+2];
  const float4 va = ((const float4*)(y3 + (size_t)e0*CH))[q];
  const float4 vb = ((const float4*)(y3 + (size_t)e1*CH))[q];
  const float4 vc = ((const float4*)(y3 + (size_t)e2*CH))[q];
  float4 r;
  r.x = fminf(va.x, fminf(vb.x, vc.x));
  r.y = fminf(va.y, fminf(vb.y, vc.y));
  r.z = fminf(va.z, fminf(vb.z, vc.z));
  r.w = fminf(va.w, fminf(vb.w, vc.w));
  ((float4*)(mn + (size_t)mo*CH))[q] = r;
}

// =====================================================================
extern "C" void kernel_launch(void* const* d_in, const int* in_sizes, int n_in,
                              void* d_out, int out_size, void* d_ws, size_t ws_size,
                              hipStream_t stream){
  const float* node_embeds = (const float*)d_in[0];
  const float* W_hg  = (const float*)d_in[1];
  const float* b_hg  = (const float*)d_in[2];
  const float* W_lin = (const float*)d_in[3];
  const float* b_lin = (const float*)d_in[4];
  const float* W_gcn = (const float*)d_in[5];
  const float* b_gcn = (const float*)d_in[6];
  const float* W_lin2= (const float*)d_in[7];
  const float* b_lin2= (const float*)d_in[8];
  const float* W_lin3= (const float*)d_in[9];
  const float* b_lin3= (const float*)d_in[10];
  const float* W_out = (const float*)d_in[11];
  const float* b_out = (const float*)d_in[12];
  const int* src  = (const int*)d_in[13];
  const int* he   = src + NNZ_CNT;
  const int* erow = (const int*)d_in[14];
  const int* ecol = erow + EE_CNT;
  const int* msrc = (const int*)d_in[15];   // motif member hyperedge ids (3 per motif, contiguous)

  uint8_t* wp = (uint8_t*)d_ws;
  auto take = [&](size_t bytes)->void*{
    void* p = (void*)wp; wp += (bytes + 255) & ~(size_t)255; return p;
  };
  float* P    = (float*)take((size_t)N_EDGES*CH*4);   // 64MB: P, later y3
  float* T    = (float*)take((size_t)N_EDGES*CH*4);   // 64MB: y_gcn, later mn
  int* b_cnt  = (int*)take(N_EDGES*4);
  int* d_cnt  = (int*)take(N_NODES*4);
  int* degc   = (int*)take(N_EDGES*4);
  int* rowptrH= (int*)take((N_EDGES+1)*4);
  int* rowptrC= (int*)take((N_EDGES+1)*4);
  int* curH   = (int*)take(N_EDGES*4);
  int* curC   = (int*)take(N_EDGES*4);
  int* colH   = (int*)take((size_t)NNZ_CNT*4);
  int* rowC   = (int*)take((size_t)EE_CNT*4);
  int* scanTmp= (int*)take(N_EDGES*4);
  int* bsum   = (int*)take(64*4);
  float* S    = (float*)take(N_NODES*N_NODES*4);
  float* xb   = (float*)take(N_NODES*CH*4);
  float* yA   = (float*)take(N_NODES*CH*4);
  float* yB   = (float*)take(N_NODES*CH*4);
  float* y2   = (float*)take(N_NODES*CH*4);
  float* G    = (float*)take(N_NODES*CH*4);
  float* Wc   = (float*)take(CH*CH_OUT*4);
  float* bc   = (float*)take(CH_OUT*4);

  hipMemsetAsync(b_cnt, 0, N_EDGES*4, stream);
  hipMemsetAsync(d_cnt, 0, N_NODES*4, stream);
  hipMemsetAsync(degc,  0, N_EDGES*4, stream);
  hipMemsetAsync(S,     0, N_NODES*N_NODES*4, stream);

  k_hist_inc<<<512,256,0,stream>>>(src, he, d_cnt, b_cnt);
  k_hist_col<<<512,256,0,stream>>>(ecol, degc);

  k_scan1<<<64,1024,0,stream>>>(b_cnt, scanTmp, bsum);
  k_scan2<<<1,64,0,stream>>>(bsum);
  k_scan3<<<256,256,0,stream>>>(scanTmp, bsum, b_cnt, rowptrH, curH);
  k_scan1<<<64,1024,0,stream>>>(degc, scanTmp, bsum);
  k_scan2<<<1,64,0,stream>>>(bsum);
  k_scan3<<<256,256,0,stream>>>(scanTmp, bsum, degc, rowptrC, curC);

  k_fillH<<<512,256,0,stream>>>(src, he, curH, colH);
  k_fillC<<<512,256,0,stream>>>(erow, ecol, curC, rowC);

  k_S<<<16384,256,0,stream>>>(rowptrH, colH, S);

  // small dense chain (all 256x256)
  k_mm256<0><<<256,256,0,stream>>>(node_embeds, W_hg, xb, nullptr, nullptr); // x = NE@W_hg
  k_mm256<1><<<256,256,0,stream>>>(S, xb, yA, d_cnt, b_hg);   // yA = lrelu(dinv*(S@x)+b_hg)
  k_atA<<<256,256,0,stream>>>(yA, yB);                        // yB = yA^T @ yA
  k_mm256<2><<<256,256,0,stream>>>(yB, W_lin, y2, nullptr, b_lin); // y2 = lrelu(yB@W_lin+b_lin)
  k_mm256<0><<<256,256,0,stream>>>(y2, W_gcn, G, nullptr, nullptr); // G = y2@W_gcn
  k_combo<<<257,64,0,stream>>>(W_lin3, b_lin3, W_out, b_out, Wc, bc);

  k_P<<<N_EDGES,64,0,stream>>>(rowptrH, colH, rowptrC, rowC, b_cnt, degc, P);

  dim3 g1(1024, 4);
  k_gemm<0><<<g1,256,0,stream>>>(P, G, T, 256, 256, b_gcn);       // y_gcn = P@G + b_gcn
  k_gemm<1><<<g1,256,0,stream>>>(T, W_lin2, P, 256, 256, b_lin2); // y3 = lrelu(y_gcn@W_lin2+b_lin2)

  k_mn<<<16384,256,0,stream>>>(P, msrc, T);                       // mn = min3 rows of y3

  dim3 g3(1024, 1);
  k_gemm<0><<<g3,256,0,stream>>>(T, Wc, (float*)d_out, 256, CH_OUT, bc); // out = mn@Wc + bc
}